// Round 8
// baseline (5136.341 us; speedup 1.0000x reference)
//
#include <hip/hip_runtime.h>
#include <stdint.h>

#define VOCAB 50257
#define B 256
#define EMB 300
#define HID 700
#define G3 2100          // 3*HID
#define ZDIM 500
#define ATTR_EMBD 200
#define MAXLEN 30
#define SEQ 31           // MAXLEN+1
#define HY_ELEMS (B*SEQ*HID)
#define KP 704           // HID padded to mult of 32
#define NKT 22           // KP/32 k-tiles
#define KIH 320          // EMB padded to mult of 32
#define VPAD 50304       // VOCAB padded to mult of 128 (393*128)
#define NVT 393          // VPAD/128
#define MPAD 2112        // G3 padded to 33*64
#define SOS_IDX 1
#define EOS_IDX 2
// w tiled chunk: per (panel, kt): [part(2)][4096 halves]; half idx = (kc*128+row)*8+e
#define CHUNK 4096
#define TILE_STRIDE ((size_t)NKT * 2 * CHUNK)   // halves per v-panel
// h tiled image: per (c-slice of 32 b-rows, kt): [part(2)][1024 halves];
// half idx = (kc*32+row)*8+e
#define HT_KT 2048                               // halves per kt (both parts)
#define HT_C ((size_t)NKT * HT_KT)               // 45056 halves per c-slice
#define NITEMS 3144                              // 393 panels * 8 b-slices
#define NBLK 1048                                // 8 XCDs * 131 blocks, 3 items each

typedef _Float16 half8 __attribute__((ext_vector_type(8)));
typedef _Float16 half4 __attribute__((ext_vector_type(4)));
typedef float f32x4 __attribute__((ext_vector_type(4)));

// ---------------- global_load_lds helper (16B per lane, dest = wave base + lane*16)
typedef const __attribute__((address_space(1))) void* gas1_t;
typedef __attribute__((address_space(3))) void* las3_t;
__device__ __forceinline__ void gload_lds16(const void* g, void* l) {
  __builtin_amdgcn_global_load_lds((gas1_t)g, (las3_t)l, 16, 0, 0);
}

// ---------------- threefry2x32 (JAX-exact, 20 rounds) ----------------
__device__ __forceinline__ uint32_t rotl32(uint32_t x, int r) {
  return (x << r) | (x >> (32 - r));
}

__device__ __forceinline__ void threefry2x32(uint32_t k0, uint32_t k1,
                                             uint32_t x0, uint32_t x1,
                                             uint32_t& o0, uint32_t& o1) {
  const uint32_t ks2 = k0 ^ k1 ^ 0x1BD11BDAu;
  x0 += k0; x1 += k1;
#define TF_R4(a, b, c, d)                                     \
  x0 += x1; x1 = rotl32(x1, a); x1 ^= x0;                     \
  x0 += x1; x1 = rotl32(x1, b); x1 ^= x0;                     \
  x0 += x1; x1 = rotl32(x1, c); x1 ^= x0;                     \
  x0 += x1; x1 = rotl32(x1, d); x1 ^= x0;
  TF_R4(13, 15, 26, 6)  x0 += k1;  x1 += ks2 + 1u;
  TF_R4(17, 29, 16, 24) x0 += ks2; x1 += k0 + 2u;
  TF_R4(13, 15, 26, 6)  x0 += k0;  x1 += k1 + 3u;
  TF_R4(17, 29, 16, 24) x0 += k1;  x1 += ks2 + 4u;
  TF_R4(13, 15, 26, 6)  x0 += ks2; x1 += k0 + 5u;
#undef TF_R4
  o0 = x0; o1 = x1;
}

// __logf: ~1-2 ulp fast log; gumbel perturbation ~1e-6 abs -> flip prob ~1e-2
// over all 7680 samples (vs libm logf's ~30-instr chain x2 per sample).
__device__ __forceinline__ unsigned long long gumbel_pack(float s, uint32_t key0,
                                                          uint32_t key1, int b, int v) {
  uint32_t j = (uint32_t)(b * VOCAB + v);
  uint32_t o0, o1;
  threefry2x32(key0, key1, 0u, j, o0, o1);
  uint32_t bits = o0 ^ o1;
  float f = __uint_as_float((bits >> 9) | 0x3f800000u) - 1.0f;
  float u = fmaxf(f, 1.17549435e-38f);
  float g = -__logf(-__logf(u));
  s += g;
  uint32_t us = __float_as_uint(s);
  us = (us & 0x80000000u) ? ~us : (us | 0x80000000u);
  return ((unsigned long long)us << 32) | (uint32_t)(~(uint32_t)v);
}

// split helper: val*scale -> {fp16 hi, fp16 lo=residual*2048}
struct hl16 { _Float16 hi, lo; };
__device__ __forceinline__ hl16 split16(float val, float scale) {
  float s = val * scale;
  _Float16 h = (_Float16)s;
  hl16 r;
  r.hi = h;
  r.lo = (_Float16)((s - (float)h) * 2048.0f);
  return r;
}

// ---------------- init ----------------
__global__ void k_init(const float* __restrict__ z, const int* __restrict__ l,
                       const float* __restrict__ attr_w, const float* __restrict__ emb_w,
                       float* __restrict__ hbuf0, uint32_t* __restrict__ keys,
                       unsigned long long* __restrict__ slots,
                       int* __restrict__ tok, float* __restrict__ y_out,
                       _Float16* __restrict__ h_hi, _Float16* __restrict__ h_lo,
                       _Float16* __restrict__ ht,
                       _Float16* __restrict__ x0_hi, _Float16* __restrict__ x0_lo,
                       _Float16* __restrict__ xe_hi, _Float16* __restrict__ xe_lo,
                       int full) {
  int idx = blockIdx.x * blockDim.x + threadIdx.x;
  if (idx < B * HID) {
    int b = idx / HID, i = idx % HID;
    float v = (i < ZDIM) ? z[b * ZDIM + i]
                         : attr_w[l[b] * ATTR_EMBD + (i - ZDIM)];
    hbuf0[idx] = v;
    hl16 r = split16(v, 8.0f);
    h_hi[b * KP + i] = r.hi;
    h_lo[b * KP + i] = r.lo;
  }
  if (idx < MAXLEN) {
    uint32_t o0, o1;
    threefry2x32(0u, 42u, 0u, (uint32_t)idx, o0, o1);
    keys[2 * idx] = o0; keys[2 * idx + 1] = o1;
  }
  if (idx < MAXLEN * B) slots[idx] = 0ull;
  if (idx < B) {
    tok[idx] = SOS_IDX;
    tok[31 * B + idx] = EOS_IDX;
    y_out[idx * SEQ + MAXLEN] = 2.0f;
  }
  if (idx < B * 4) {  // zero k-pad (700..703) of linear + tiled h
    int b = idx >> 2, k = HID + (idx & 3);
    h_hi[b * KP + k] = (_Float16)0.0f;
    h_lo[b * KP + k] = (_Float16)0.0f;
    int c = b >> 5, row = b & 31;               // kt=21, kc=3
    size_t tb = (size_t)c * HT_C + (size_t)21 * HT_KT + (size_t)(3 * 32 + row) * 8
              + (k & 7);
    ht[tb] = (_Float16)0.0f;
    ht[tb + 1024] = (_Float16)0.0f;
  }
  if (full && idx < KIH) {
    float v0 = (idx < EMB) ? emb_w[SOS_IDX * EMB + idx] : 0.0f;
    float ve = (idx < EMB) ? emb_w[EOS_IDX * EMB + idx] : 0.0f;
    hl16 r0 = split16(v0, 8.0f);
    hl16 re = split16(ve, 8.0f);
    for (int b = 0; b < B; ++b) {  // broadcast rows (all batches share SOS/EOS)
      x0_hi[b * KIH + idx] = r0.hi; x0_lo[b * KIH + idx] = r0.lo;
      xe_hi[b * KIH + idx] = re.hi; xe_lo[b * KIH + idx] = re.lo;
    }
  }
}

// ---------------- logits w split -> TILED fragment-image layout ----------------
__global__ void k_wsplit(const float* __restrict__ out_w, _Float16* __restrict__ wt) {
  size_t idx = (size_t)blockIdx.x * blockDim.x + threadIdx.x;
  if (idx >= (size_t)NVT * NKT * 1024) return;
  int h4 = (int)(idx & 1023);
  int ktp = (int)(idx >> 10);
  int kt = ktp % NKT, p = ktp / NKT;
  int slot4 = h4 >> 1, e0 = (h4 & 1) * 4;
  int kc = slot4 >> 7, row = slot4 & 127;
  int v = p * 128 + row;
  int k = kt * 32 + kc * 8 + e0;
  float x[4];
  if (v < VOCAB && k + 3 < HID) {
    const float4 xv = *(const float4*)&out_w[(size_t)v * HID + k];
    x[0] = xv.x; x[1] = xv.y; x[2] = xv.z; x[3] = xv.w;
  } else {
#pragma unroll
    for (int j = 0; j < 4; ++j)
      x[j] = (v < VOCAB && k + j < HID) ? out_w[(size_t)v * HID + k + j] : 0.0f;
  }
  half4 hi, lo;
#pragma unroll
  for (int j = 0; j < 4; ++j) {
    hl16 r = split16(x[j], 64.0f);
    hi[j] = r.hi; lo[j] = r.lo;
  }
  size_t base = (size_t)p * TILE_STRIDE + (size_t)kt * 2 * CHUNK + slot4 * 8 + e0;
  *(half4*)&wt[base] = hi;
  *(half4*)&wt[base + CHUNK] = lo;
}

// ---------------- generic gate-weight split (Msrc x Ksrc -> MPAD x Kpad) ----------------
__global__ void k_gwsplit(const float* __restrict__ src, _Float16* __restrict__ hi,
                          _Float16* __restrict__ lo, int Msrc, int Ksrc, int Kpad,
                          int tot4) {
  int idx = blockIdx.x * blockDim.x + threadIdx.x;
  if (idx >= tot4) return;
  size_t i4 = (size_t)idx * 4;
  int m = (int)(i4 / Kpad), k = (int)(i4 % Kpad);
  half4 h, l;
#pragma unroll
  for (int j = 0; j < 4; ++j) {
    float x = (m < Msrc && k + j < Ksrc) ? src[(size_t)m * Ksrc + k + j] : 0.0f;
    hl16 r = split16(x, 64.0f);
    h[j] = r.hi; l[j] = r.lo;
  }
  *(half4*)&hi[i4] = h;
  *(half4*)&lo[i4] = l;
}

// ---------------- MFMA gates: 64j x 64b blocks, 4 waves (32x32), 2-phase gll+dbuf ----
__global__ __launch_bounds__(256, 4)
void k_gates2(const _Float16* __restrict__ wih_hi, const _Float16* __restrict__ wih_lo,
              const _Float16* __restrict__ whh_hi, const _Float16* __restrict__ whh_lo,
              const _Float16* __restrict__ x_hi, const _Float16* __restrict__ x_lo,
              const _Float16* __restrict__ h_hi, const _Float16* __restrict__ h_lo,
              float* __restrict__ gi, float* __restrict__ gh) {
  const int zz = blockIdx.z;
  const _Float16* __restrict__ Whi = zz ? whh_hi : wih_hi;
  const _Float16* __restrict__ Wlo = zz ? whh_lo : wih_lo;
  const _Float16* __restrict__ Xhi = zz ? h_hi : x_hi;
  const _Float16* __restrict__ Xlo = zz ? h_lo : x_lo;
  const int Kz = zz ? KP : KIH;
  float* __restrict__ out = zz ? gh : gi;

  const int jbase = blockIdx.x * 64;
  const int bbase = blockIdx.y * 64;
  __shared__ float4 lds[2][4][256];   // [buf][whi,wlo,xhi,xlo][kc*64+row]
  const int tid = threadIdx.x, lane = tid & 63, wid = tid >> 6;
  const int wj = wid >> 1, wb2 = wid & 1;
  const size_t wrow = (size_t)(jbase + lane) * Kz;   // stage: kc=wid, row=lane
  const size_t xrow = (size_t)(bbase + lane) * Kz;

  f32x4 acc_h[2][2], acc_x[2][2];
#pragma unroll
  for (int i = 0; i < 2; ++i)
#pragma unroll
    for (int j = 0; j < 2; ++j) { acc_h[i][j] = (f32x4)0.0f; acc_x[i][j] = (f32x4)0.0f; }

#define GSTAGE(bf, k0)                                                   \
  {                                                                      \
    gload_lds16(Whi + wrow + (k0) + wid * 8, &lds[bf][0][wid * 64]);     \
    gload_lds16(Wlo + wrow + (k0) + wid * 8, &lds[bf][1][wid * 64]);     \
    gload_lds16(Xhi + xrow + (k0) + wid * 8, &lds[bf][2][wid * 64]);     \
    gload_lds16(Xlo + xrow + (k0) + wid * 8, &lds[bf][3][wid * 64]);     \
  }

  const int nt = Kz / 32;
  GSTAGE(0, 0)
  for (int kt = 0; kt < nt; ++kt) {
    const int cur = kt & 1;
    __syncthreads();                       // drains staged loads for buf[cur]
    if (kt + 1 < nt) GSTAGE(cur ^ 1, (kt + 1) * 32)
    const int kcf = (lane >> 4) * 64 + (lane & 15);
    half8 a_hi[2], a_lo[2];
#pragma unroll
    for (int fv = 0; fv < 2; ++fv) {
      int s = kcf + wj * 32 + fv * 16;
      a_hi[fv] = *(const half8*)&lds[cur][0][s];
      a_lo[fv] = *(const half8*)&lds[cur][1][s];
    }
#pragma unroll
    for (int fb = 0; fb < 2; ++fb) {
      int s = kcf + wb2 * 32 + fb * 16;
      half8 b_hi = *(const half8*)&lds[cur][2][s];
      half8 b_lo = *(const half8*)&lds[cur][3][s];
#pragma unroll
      for (int fv = 0; fv < 2; ++fv) {
        acc_h[fv][fb] = __builtin_amdgcn_mfma_f32_16x16x32_f16(a_hi[fv], b_hi,
                                                               acc_h[fv][fb], 0, 0, 0);
        acc_x[fv][fb] = __builtin_amdgcn_mfma_f32_16x16x32_f16(a_hi[fv], b_lo,
                                                               acc_x[fv][fb], 0, 0, 0);
        acc_x[fv][fb] = __builtin_amdgcn_mfma_f32_16x16x32_f16(a_lo[fv], b_hi,
                                                               acc_x[fv][fb], 0, 0, 0);
      }
    }
  }
#undef GSTAGE

  const float c1 = 1.0f / 2048.0f, c2 = 1.0f / 512.0f;
#pragma unroll
  for (int fb = 0; fb < 2; ++fb) {
    const int b = bbase + wb2 * 32 + fb * 16 + (lane & 15);
#pragma unroll
    for (int fv = 0; fv < 2; ++fv) {
#pragma unroll
      for (int r = 0; r < 4; ++r) {
        int j = jbase + wj * 32 + fv * 16 + (lane >> 4) * 4 + r;
        if (j < G3)
          out[b * G3 + j] = (acc_h[fv][fb][r] + acc_x[fv][fb][r] * c1) * c2;
      }
    }
  }
}

// ---------------- fp32 gates fallback ----------------
__global__ void k_gates(const float* __restrict__ W_ih, const float* __restrict__ W_hh,
                        const float* __restrict__ emb_w, const float* __restrict__ hprev,
                        const int* __restrict__ tok,
                        float* __restrict__ gi, float* __restrict__ gh) {
  const int zz = blockIdx.z;
  const float* __restrict__ W = zz ? W_hh : W_ih;
  const int K = zz ? HID : EMB;
  float* __restrict__ out = zz ? gh : gi;
  __shared__ float w_lds[20][36];
  __shared__ float xh_lds[20][36];
  const int jbase = blockIdx.x * 32;
  const int bbase = blockIdx.y * 32;
  const int tid = threadIdx.x;
  const int tj = tid % 16, tb = tid / 16;
  float a00 = 0.f, a01 = 0.f, a10 = 0.f, a11 = 0.f;
  for (int k0 = 0; k0 < K; k0 += 20) {
    for (int idx = tid; idx < 640; idx += 256) {
      int col = idx / 20, kk = idx % 20;
      int j = jbase + col;
      w_lds[kk][col] = (j < G3) ? W[j * K + k0 + kk] : 0.0f;
      int b = bbase + col;
      float xv;
      if (zz) xv = hprev[b * HID + k0 + kk];
      else    xv = emb_w[tok[b] * EMB + k0 + kk];
      xh_lds[kk][col] = xv;
    }
    __syncthreads();
#pragma unroll
    for (int kk = 0; kk < 20; ++kk) {
      float w0 = w_lds[kk][tj * 2], w1 = w_lds[kk][tj * 2 + 1];
      float h0 = xh_lds[kk][tb * 2], h1 = xh_lds[kk][tb * 2 + 1];
      a00 += w0 * h0; a01 += w0 * h1;
      a10 += w1 * h0; a11 += w1 * h1;
    }
    __syncthreads();
  }
  int j0 = jbase + tj * 2, b0 = bbase + tb * 2;
  if (j0 < G3)     { out[b0 * G3 + j0] = a00;     out[(b0 + 1) * G3 + j0] = a01; }
  if (j0 + 1 < G3) { out[b0 * G3 + j0 + 1] = a10; out[(b0 + 1) * G3 + j0 + 1] = a11; }
}

// ---------------- pointwise GRU update + h fp16-split (linear for gates, tiled for logits)
__global__ void k_hnew(const float* __restrict__ gi, const float* __restrict__ gh,
                       const float* __restrict__ b_ih, const float* __restrict__ b_hh,
                       const float* __restrict__ hprev, float* __restrict__ hnext,
                       float* __restrict__ hy, _Float16* __restrict__ h_hi,
                       _Float16* __restrict__ h_lo, _Float16* __restrict__ ht, int t) {
  int idx = blockIdx.x * blockDim.x + threadIdx.x;
  if (idx >= B * HID) return;
  int b = idx / HID, i = idx % HID;
  float ir = gi[b * G3 + i]            + b_ih[i];
  float iz = gi[b * G3 + HID + i]      + b_ih[HID + i];
  float in_ = gi[b * G3 + 2 * HID + i] + b_ih[2 * HID + i];
  float hr = gh[b * G3 + i]            + b_hh[i];
  float hz = gh[b * G3 + HID + i]      + b_hh[HID + i];
  float hn = gh[b * G3 + 2 * HID + i]  + b_hh[2 * HID + i];
  float r  = 1.0f / (1.0f + expf(-(ir + hr)));
  float zg = 1.0f / (1.0f + expf(-(iz + hz)));
  float n  = tanhf(in_ + r * hn);
  float h  = (1.0f - zg) * n + zg * hprev[idx];
  hnext[idx] = h;
  hy[(size_t)b * SEQ * HID + (size_t)t * HID + i] = h;
  hl16 rr = split16(h, 8.0f);
  h_hi[b * KP + i] = rr.hi;
  h_lo[b * KP + i] = rr.lo;
  // tiled image for k_logits4: c=b>>5 (32-row slices), row=b&31,
  // kt=i>>5, kc=(i>>3)&3, e=i&7
  int c = b >> 5, row = b & 31;
  size_t tb = (size_t)c * HT_C + (size_t)(i >> 5) * HT_KT
            + (size_t)((((i >> 3) & 3) * 32 + row) * 8) + (i & 7);
  ht[tb] = rr.hi;
  ht[tb + 1024] = rr.lo;
}

// ---------------- MFMA logits v5: 32x32 wave tiles, 4 waves/SIMD occupancy ----
// 3144 items = (panel p, 32-row b-slice c). Grid 1048 = 8 XCDs x 131 blocks,
// each block 3 consecutive items (same/adjacent panel -> w L2-hot, XCD-chunked).
// w LDS-staged (dbuf 2x16KB); h (L2-hot) direct-to-reg issued BEFORE the stage
// so MFMA's vmcnt wait leaves the stage loads in flight.
__global__ __launch_bounds__(256, 4)
void k_logits4(const _Float16* __restrict__ wt, const _Float16* __restrict__ ht,
               const float* __restrict__ out_b, const uint32_t* __restrict__ keys,
               unsigned long long* __restrict__ slot, int t) {
  __shared__ float4 ldsw[2][1024];   // [buf][ w_hi: 0..511 | w_lo: 512..1023 ]
  const int tid = threadIdx.x;
  const int lane = tid & 63;
  const int wid = tid >> 6;
  const int work = (blockIdx.x & 7) * 131 + (blockIdx.x >> 3);  // XCD-chunked

  const uint32_t key0 = keys[2 * t], key1 = keys[2 * t + 1];
  const float c1 = 1.0f / 2048.0f, c2 = 1.0f / 512.0f;

  const int wrow = (lane >> 4) * 128 + (lane & 15) + wid * 32;  // float4 idx in w buf
  const int hrow = ((lane >> 4) * 32 + (lane & 15)) * 8;        // half idx in h chunk

#define STAGE4(bf, ktv)                                                        \
  {                                                                            \
    _Pragma("unroll")                                                          \
    for (int j = 0; j < 4; ++j) {                                              \
      const int s = wid * 4 + j;                                               \
      gload_lds16(wp + (size_t)(ktv) * (2 * CHUNK) + (size_t)(s >> 3) * CHUNK  \
                      + (s & 7) * 512 + lane * 8,                              \
                  &ldsw[bf][s * 64]);                                          \
    }                                                                          \
  }

  for (int it = 0; it < 3; ++it) {
    const int item = work * 3 + it;
    const int p = item >> 3, cc = item & 7;
    const int vbase = p * 128, bbase = cc * 32;
    const _Float16* __restrict__ wp = wt + (size_t)p * TILE_STRIDE;
    const _Float16* __restrict__ hq0 = ht + (size_t)cc * HT_C;

    f32x4 acc_h[2][2], acc_x[2][2];
#pragma unroll
    for (int i = 0; i < 2; ++i)
#pragma unroll
      for (int j = 0; j < 2; ++j) { acc_h[i][j] = (f32x4)0.0f; acc_x[i][j] = (f32x4)0.0f; }

    STAGE4(0, 0)
    for (int kt = 0; kt < NKT; ++kt) {
      const int cur = kt & 1;
      __syncthreads();                     // drains buf[cur]'s staged loads
      // h fragments direct to regs (issued before next stage: MFMA's vmcnt
      // wait covers only these, stage stays in flight)
      const _Float16* hq = hq0 + (size_t)kt * HT_KT;
      half8 hC_hi[2], hC_lo[2];
      hC_hi[0] = *(const half8*)(hq + hrow);
      hC_hi[1] = *(const half8*)(hq + hrow + 128);
      hC_lo[0] = *(const half8*)(hq + 1024 + hrow);
      hC_lo[1] = *(const half8*)(hq + 1024 + hrow + 128);
      if (kt + 1 < NKT) STAGE4(cur ^ 1, kt + 1)
      half8 wA_hi[2], wA_lo[2];
      wA_hi[0] = *(const half8*)&ldsw[cur][wrow];
      wA_hi[1] = *(const half8*)&ldsw[cur][wrow + 16];
      wA_lo[0] = *(const half8*)&ldsw[cur][wrow + 512];
      wA_lo[1] = *(const half8*)&ldsw[cur][wrow + 512 + 16];
#pragma unroll
      for (int fb = 0; fb < 2; ++fb) {
#pragma unroll
        for (int fv = 0; fv < 2; ++fv) {
          acc_h[fv][fb] = __builtin_amdgcn_mfma_f32_16x16x32_f16(
              wA_hi[fv], hC_hi[fb], acc_h[fv][fb], 0, 0, 0);
          acc_x[fv][fb] = __builtin_amdgcn_mfma_f32_16x16x32_f16(
              wA_hi[fv], hC_lo[fb], acc_x[fv][fb], 0, 0, 0);
          acc_x[fv][fb] = __builtin_amdgcn_mfma_f32_16x16x32_f16(
              wA_lo[fv], hC_hi[fb], acc_x[fv][fb], 0, 0, 0);
        }
      }
    }

    // epilogue: logits + gumbel + argmax (layout identical to prior rounds,
    // with 32v wave tile: v = vbase + wid*32 + fv*16 + (lane>>4)*4 + r)
#pragma unroll
    for (int fb = 0; fb < 2; ++fb) {
      const int b = bbase + fb * 16 + (lane & 15);
      unsigned long long best = 0ull;
#pragma unroll
      for (int fv = 0; fv < 2; ++fv) {
#pragma unroll
        for (int r = 0; r < 4; ++r) {
          int v = vbase + wid * 32 + fv * 16 + (lane >> 4) * 4 + r;
          if (v < VOCAB) {
            float s = (acc_h[fv][fb][r] + acc_x[fv][fb][r] * c1) * c2 + out_b[v];
            unsigned long long cand = gumbel_pack(s, key0, key1, b, v);
            if (cand > best) best = cand;
          }
        }
      }
      unsigned long long o;
      o = __shfl_xor(best, 16, 64); if (o > best) best = o;
      o = __shfl_xor(best, 32, 64); if (o > best) best = o;
      if ((lane >> 4) == 0) atomicMax(&slot[b], best);
    }
    // no extra barrier needed: buf0 was last read at kt=20, before kt=21's
    // top barrier -> next item's STAGE4(0,0) is safe.
  }
#undef STAGE4
}

// ---------------- fp32 logits fallback ----------------
#define WPITCH 68
#define HPITCH 260
__global__ __launch_bounds__(256)
void k_logits_f32(const float* __restrict__ h, const float* __restrict__ out_w,
                  const float* __restrict__ out_b, const uint32_t* __restrict__ keys,
                  unsigned long long* __restrict__ slot, int t) {
  __shared__ float w_lds[20][WPITCH];
  __shared__ float h_lds[20][HPITCH];
  const int vbase = blockIdx.x * 64;
  const int tid = threadIdx.x;
  const int tv = tid % 8, tb = tid / 8;
  float acc[8][8];
#pragma unroll
  for (int i = 0; i < 8; ++i)
#pragma unroll
    for (int j = 0; j < 8; ++j) acc[i][j] = 0.f;

  for (int k0 = 0; k0 < HID; k0 += 20) {
    for (int idx = tid; idx < 64 * 20; idx += 256) {
      int vv = idx / 20, kk = idx % 20;
      int v = vbase + vv;
      w_lds[kk][vv] = (v < VOCAB) ? out_w[(size_t)v * HID + k0 + kk] : 0.0f;
    }
    for (int idx = tid; idx < 256 * 20; idx += 256) {
      int bb = idx / 20, kk = idx % 20;
      h_lds[kk][bb] = h[bb * HID + k0 + kk];
    }
    __syncthreads();
#pragma unroll
    for (int kk = 0; kk < 20; ++kk) {
      float wv[8], hv[8];
      *(float4*)&wv[0] = *(const float4*)&w_lds[kk][tv * 8];
      *(float4*)&wv[4] = *(const float4*)&w_lds[kk][tv * 8 + 4];
      *(float4*)&hv[0] = *(const float4*)&h_lds[kk][tb * 8];
      *(float4*)&hv[4] = *(const float4*)&h_lds[kk][tb * 8 + 4];
#pragma unroll
      for (int iv = 0; iv < 8; ++iv)
#pragma unroll
        for (int ib = 0; ib < 8; ++ib) acc[iv][ib] += wv[iv] * hv[ib];
    }
    __syncthreads();
  }

  const uint32_t key0 = keys[2 * t], key1 = keys[2 * t + 1];
#pragma unroll
  for (int ib = 0; ib < 8; ++ib) {
    const int b = tb * 8 + ib;
    unsigned long long best = 0ull;
#pragma unroll
    for (int iv = 0; iv < 8; ++iv) {
      int v = vbase + tv * 8 + iv;
      if (v >= VOCAB) continue;
      unsigned long long cand = gumbel_pack(acc[iv][ib] + out_b[v], key0, key1, b, v);
      if (cand > best) best = cand;
    }
#pragma unroll
    for (int off = 1; off < 8; off <<= 1) {
      unsigned long long other = __shfl_xor(best, off, 64);
      if (other > best) best = other;
    }
    if (tv == 0) atomicMax(&slot[b], best);
  }
}

// ---------------- token extraction + emb gather/split ----------------
__global__ void k_tok2(const unsigned long long* __restrict__ slot,
                       const float* __restrict__ emb_w,
                       int* __restrict__ tok_next, float* __restrict__ y_out,
                       _Float16* __restrict__ xc_hi, _Float16* __restrict__ xc_lo,
                       int t, int full) {
  const int b = blockIdx.x;
  const int c = threadIdx.x;   // 128 threads
  unsigned long long p = slot[b];
  uint32_t v = ~((uint32_t)(p & 0xFFFFFFFFull));
  if (c == 0) {
    tok_next[b] = (int)v;
    y_out[b * SEQ + t] = (float)v;
  }
  if (!full) return;
  if (c < 75) {
    float4 xv = *(const float4*)&emb_w[(size_t)v * EMB + c * 4];
    half4 hi, lo;
    hl16 r0 = split16(xv.x, 8.0f); hi[0] = r0.hi; lo[0] = r0.lo;
    hl16 r1 = split16(xv.y, 8.0f); hi[1] = r1.hi; lo[1] = r1.lo;
    hl16 r2 = split16(xv.z, 8.0f); hi[2] = r2.hi; lo[2] = r2.lo;
    hl16 r3 = split16(xv.w, 8.0f); hi[3] = r3.hi; lo[3] = r3.lo;
    *(half4*)&xc_hi[b * KIH + c * 4] = hi;
    *(half4*)&xc_lo[b * KIH + c * 4] = lo;
  } else if (c < 80) {
    *(half4*)&xc_hi[b * KIH + c * 4] = (half4)(_Float16)0.0f;
    *(half4*)&xc_lo[b * KIH + c * 4] = (half4)(_Float16)0.0f;
  }
}

// ---------------- host launch ----------------
extern "C" void kernel_launch(void* const* d_in, const int* in_sizes, int n_in,
                              void* d_out, int out_size, void* d_ws, size_t ws_size,
                              hipStream_t stream) {
  const float* z      = (const float*)d_in[0];
  const int*   l      = (const int*)  d_in[1];
  const float* emb_w  = (const float*)d_in[2];
  const float* attr_w = (const float*)d_in[3];
  const float* W_ih   = (const float*)d_in[4];
  const float* W_hh   = (const float*)d_in[5];
  const float* b_ih   = (const float*)d_in[6];
  const float* b_hh   = (const float*)d_in[7];
  const float* out_w  = (const float*)d_in[8];
  const float* out_b  = (const float*)d_in[9];

  float* hy    = (float*)d_out;
  float* y_out = (float*)d_out + HY_ELEMS;

  char* ws = (char*)d_ws;
  size_t off = 0;
  uint32_t* keys            = (uint32_t*)(ws + off);           off += 256;
  unsigned long long* slots = (unsigned long long*)(ws + off); off += (size_t)MAXLEN * B * 8;
  int* tokbuf               = (int*)(ws + off);                off += (size_t)32 * B * 4;
  float* hbuf               = (float*)(ws + off);              off += (size_t)2 * B * HID * 4;
  float* gi                 = (float*)(ws + off);              off += (size_t)B * G3 * 4;
  float* gh                 = (float*)(ws + off);              off += (size_t)B * G3 * 4;
  _Float16* h_hi            = (_Float16*)(ws + off);           off += (size_t)B * KP * 2;
  _Float16* h_lo            = (_Float16*)(ws + off);           off += (size_t)B * KP * 2;
  _Float16* ht              = (_Float16*)(ws + off);           off += (size_t)8 * HT_C * 2;
  _Float16* wt              = (_Float16*)(ws + off);           off += (size_t)NVT * TILE_STRIDE * 2;
  const size_t tier1_end = off;
  _Float16* wih_hi          = (_Float16*)(ws + off);           off += (size_t)MPAD * KIH * 2;
  _Float16* wih_lo          = (_Float16*)(ws + off);           off += (size_t)MPAD * KIH * 2;
  _Float16* whh_hi          = (_Float16*)(ws + off);           off += (size_t)MPAD * KP * 2;
  _Float16* whh_lo          = (_Float16*)(ws + off);           off += (size_t)MPAD * KP * 2;
  _Float16* x0_hi           = (_Float16*)(ws + off);           off += (size_t)B * KIH * 2;
  _Float16* x0_lo           = (_Float16*)(ws + off);           off += (size_t)B * KIH * 2;
  _Float16* xe_hi           = (_Float16*)(ws + off);           off += (size_t)B * KIH * 2;
  _Float16* xe_lo           = (_Float16*)(ws + off);           off += (size_t)B * KIH * 2;
  _Float16* xc_hi           = (_Float16*)(ws + off);           off += (size_t)B * KIH * 2;
  _Float16* xc_lo           = (_Float16*)(ws + off);           off += (size_t)B * KIH * 2;
  const size_t tier2_end = off;
  const int tier = (ws_size >= tier2_end) ? 2 : ((ws_size >= tier1_end) ? 1 : 0);

  k_init<<<(B * HID + 255) / 256, 256, 0, stream>>>(
      z, l, attr_w, emb_w, hbuf, keys, slots, tokbuf, y_out, h_hi, h_lo, ht,
      x0_hi, x0_lo, xe_hi, xe_lo, (tier == 2) ? 1 : 0);

  if (tier >= 1) {
    size_t tot = (size_t)NVT * NKT * 1024;
    k_wsplit<<<(int)((tot + 255) / 256), 256, 0, stream>>>(out_w, wt);
  }
  if (tier == 2) {
    int tih = MPAD * KIH / 4, thh = MPAD * KP / 4;
    k_gwsplit<<<(tih + 255) / 256, 256, 0, stream>>>(W_ih, wih_hi, wih_lo, G3, EMB, KIH, tih);
    k_gwsplit<<<(thh + 255) / 256, 256, 0, stream>>>(W_hh, whh_hi, whh_lo, G3, HID, KP, thh);
  }

  for (int t = 0; t <= MAXLEN; ++t) {
    float* hprev = hbuf + (t % 2) * B * HID;
    float* hnext = hbuf + ((t + 1) % 2) * B * HID;

    if (tier == 2) {
      const _Float16* xh = (t == 0) ? x0_hi : ((t == MAXLEN) ? xe_hi : xc_hi);
      const _Float16* xl = (t == 0) ? x0_lo : ((t == MAXLEN) ? xe_lo : xc_lo);
      dim3 g2(33, 4, 2);
      k_gates2<<<g2, 256, 0, stream>>>(wih_hi, wih_lo, whh_hi, whh_lo,
                                       xh, xl, h_hi, h_lo, gi, gh);
    } else {
      const int* tok_t = tokbuf + ((t == MAXLEN) ? 31 : t) * B;
      dim3 ggrid(66, 8, 2);
      k_gates<<<ggrid, 256, 0, stream>>>(W_ih, W_hh, emb_w, hprev, tok_t, gi, gh);
    }
    k_hnew<<<(B * HID + 255) / 256, 256, 0, stream>>>(gi, gh, b_ih, b_hh, hprev,
                                                      hnext, hy, h_hi, h_lo, ht, t);
    if (t < MAXLEN) {
      if (tier >= 1) {
        k_logits4<<<NBLK, 256, 0, stream>>>(wt, ht, out_b, keys,
                                            slots + (size_t)t * B, t);
      } else {
        k_logits_f32<<<(VOCAB + 63) / 64, 256, 0, stream>>>(hnext, out_w, out_b, keys,
                                                            slots + (size_t)t * B, t);
      }
      k_tok2<<<B, 128, 0, stream>>>(slots + (size_t)t * B, emb_w,
                                    tokbuf + (t + 1) * B, y_out, xc_hi, xc_lo,
                                    t, (tier == 2) ? 1 : 0);
    }
  }
}

// Round 9
// 3658.677 us; speedup vs baseline: 1.4039x; 1.4039x over previous
//
#include <hip/hip_runtime.h>
#include <stdint.h>

#define VOCAB 50257
#define B 256
#define EMB 300
#define HID 700
#define G3 2100          // 3*HID
#define ZDIM 500
#define ATTR_EMBD 200
#define MAXLEN 30
#define SEQ 31           // MAXLEN+1
#define HY_ELEMS (B*SEQ*HID)
#define KP 704           // HID padded to mult of 32
#define NKT 22           // KP/32 k-tiles
#define KIH 320          // EMB padded to mult of 32
#define VPAD 50304       // VOCAB padded to mult of 128 (393*128)
#define NVT 393          // VPAD/128
#define MPAD 2112        // G3 padded to 33*64
#define SOS_IDX 1
#define EOS_IDX 2
// tiled chunk: per (tile, kt): [part(2)][4096 halves]; half idx = (kc*128+row)*8+e
#define CHUNK 4096
#define TILE_STRIDE ((size_t)NKT * 2 * CHUNK)   // halves per v-panel / h half-tile
// logits grid: items = (panel, v-half, c-half) = 393*2*2 = 1572; 8 XCD x 197
#define NIT5 1572
#define NBLK5 1576

typedef _Float16 half8 __attribute__((ext_vector_type(8)));
typedef _Float16 half4 __attribute__((ext_vector_type(4)));
typedef float f32x4 __attribute__((ext_vector_type(4)));

// ---------------- global_load_lds helper (16B per lane, dest = wave base + lane*16)
typedef const __attribute__((address_space(1))) void* gas1_t;
typedef __attribute__((address_space(3))) void* las3_t;
__device__ __forceinline__ void gload_lds16(const void* g, void* l) {
  __builtin_amdgcn_global_load_lds((gas1_t)g, (las3_t)l, 16, 0, 0);
}

// ---------------- threefry2x32 (JAX-exact, 20 rounds) ----------------
__device__ __forceinline__ uint32_t rotl32(uint32_t x, int r) {
  return (x << r) | (x >> (32 - r));
}

__device__ __forceinline__ void threefry2x32(uint32_t k0, uint32_t k1,
                                             uint32_t x0, uint32_t x1,
                                             uint32_t& o0, uint32_t& o1) {
  const uint32_t ks2 = k0 ^ k1 ^ 0x1BD11BDAu;
  x0 += k0; x1 += k1;
#define TF_R4(a, b, c, d)                                     \
  x0 += x1; x1 = rotl32(x1, a); x1 ^= x0;                     \
  x0 += x1; x1 = rotl32(x1, b); x1 ^= x0;                     \
  x0 += x1; x1 = rotl32(x1, c); x1 ^= x0;                     \
  x0 += x1; x1 = rotl32(x1, d); x1 ^= x0;
  TF_R4(13, 15, 26, 6)  x0 += k1;  x1 += ks2 + 1u;
  TF_R4(17, 29, 16, 24) x0 += ks2; x1 += k0 + 2u;
  TF_R4(13, 15, 26, 6)  x0 += k0;  x1 += k1 + 3u;
  TF_R4(17, 29, 16, 24) x0 += k1;  x1 += ks2 + 4u;
  TF_R4(13, 15, 26, 6)  x0 += ks2; x1 += k0 + 5u;
#undef TF_R4
  o0 = x0; o1 = x1;
}

__device__ __forceinline__ unsigned long long gumbel_pack(float s, uint32_t key0,
                                                          uint32_t key1, int b, int v) {
  uint32_t j = (uint32_t)(b * VOCAB + v);
  uint32_t o0, o1;
  threefry2x32(key0, key1, 0u, j, o0, o1);
  uint32_t bits = o0 ^ o1;
  float f = __uint_as_float((bits >> 9) | 0x3f800000u) - 1.0f;
  float u = fmaxf(f, 1.17549435e-38f);
  float g = -__logf(-__logf(u));
  s += g;
  uint32_t us = __float_as_uint(s);
  us = (us & 0x80000000u) ? ~us : (us | 0x80000000u);
  return ((unsigned long long)us << 32) | (uint32_t)(~(uint32_t)v);
}

// split helper: val*scale -> {fp16 hi, fp16 lo = raw residual (UNSCALED)}.
// Unscaled lo lets hi*hi + hi*lo + lo*hi accumulate into ONE accumulator
// (halves acc registers). fp16 is floating: residual keeps full relative
// precision; subnormal-flush worst case adds ~4e-7 logit error (safe).
struct hl16 { _Float16 hi, lo; };
__device__ __forceinline__ hl16 split16(float val, float scale) {
  float s = val * scale;
  _Float16 h = (_Float16)s;
  hl16 r;
  r.hi = h;
  r.lo = (_Float16)(s - (float)h);
  return r;
}

// ---------------- init ----------------
__global__ void k_init(const float* __restrict__ z, const int* __restrict__ l,
                       const float* __restrict__ attr_w, const float* __restrict__ emb_w,
                       float* __restrict__ hbuf0, uint32_t* __restrict__ keys,
                       unsigned long long* __restrict__ slots,
                       int* __restrict__ tok, float* __restrict__ y_out,
                       _Float16* __restrict__ h_hi, _Float16* __restrict__ h_lo,
                       _Float16* __restrict__ ht,
                       _Float16* __restrict__ x0_hi, _Float16* __restrict__ x0_lo,
                       _Float16* __restrict__ xe_hi, _Float16* __restrict__ xe_lo,
                       int full) {
  int idx = blockIdx.x * blockDim.x + threadIdx.x;
  if (idx < B * HID) {
    int b = idx / HID, i = idx % HID;
    float v = (i < ZDIM) ? z[b * ZDIM + i]
                         : attr_w[l[b] * ATTR_EMBD + (i - ZDIM)];
    hbuf0[idx] = v;
    hl16 r = split16(v, 8.0f);
    h_hi[b * KP + i] = r.hi;
    h_lo[b * KP + i] = r.lo;
  }
  if (idx < MAXLEN) {
    uint32_t o0, o1;
    threefry2x32(0u, 42u, 0u, (uint32_t)idx, o0, o1);
    keys[2 * idx] = o0; keys[2 * idx + 1] = o1;
  }
  if (idx < MAXLEN * B) slots[idx] = 0ull;
  if (idx < B) {
    tok[idx] = SOS_IDX;
    tok[31 * B + idx] = EOS_IDX;
    y_out[idx * SEQ + MAXLEN] = 2.0f;
  }
  if (idx < B * 4) {  // zero k-pad (700..703) of linear + tiled h (kt=21, kc=3)
    int b = idx >> 2, k = HID + (idx & 3);
    h_hi[b * KP + k] = (_Float16)0.0f;
    h_lo[b * KP + k] = (_Float16)0.0f;
    int c = b >> 7, row = b & 127, e = k & 7;
    size_t tb = (size_t)c * TILE_STRIDE + (size_t)21 * 2 * CHUNK
              + (3 * 128 + row) * 8 + e;
    ht[tb] = (_Float16)0.0f;
    ht[tb + CHUNK] = (_Float16)0.0f;
  }
  if (full && idx < KIH) {
    float v0 = (idx < EMB) ? emb_w[SOS_IDX * EMB + idx] : 0.0f;
    float ve = (idx < EMB) ? emb_w[EOS_IDX * EMB + idx] : 0.0f;
    hl16 r0 = split16(v0, 8.0f);
    hl16 re = split16(ve, 8.0f);
    for (int b = 0; b < B; ++b) {  // broadcast rows (all batches share SOS/EOS)
      x0_hi[b * KIH + idx] = r0.hi; x0_lo[b * KIH + idx] = r0.lo;
      xe_hi[b * KIH + idx] = re.hi; xe_lo[b * KIH + idx] = re.lo;
    }
  }
}

// ---------------- logits w split -> TILED fragment-image layout ----------------
__global__ void k_wsplit(const float* __restrict__ out_w, _Float16* __restrict__ wt) {
  size_t idx = (size_t)blockIdx.x * blockDim.x + threadIdx.x;
  if (idx >= (size_t)NVT * NKT * 1024) return;
  int h4 = (int)(idx & 1023);
  int ktp = (int)(idx >> 10);
  int kt = ktp % NKT, p = ktp / NKT;
  int slot4 = h4 >> 1, e0 = (h4 & 1) * 4;
  int kc = slot4 >> 7, row = slot4 & 127;
  int v = p * 128 + row;
  int k = kt * 32 + kc * 8 + e0;
  float x[4];
  if (v < VOCAB && k + 3 < HID) {
    const float4 xv = *(const float4*)&out_w[(size_t)v * HID + k];
    x[0] = xv.x; x[1] = xv.y; x[2] = xv.z; x[3] = xv.w;
  } else {
#pragma unroll
    for (int j = 0; j < 4; ++j)
      x[j] = (v < VOCAB && k + j < HID) ? out_w[(size_t)v * HID + k + j] : 0.0f;
  }
  half4 hi, lo;
#pragma unroll
  for (int j = 0; j < 4; ++j) {
    hl16 r = split16(x[j], 64.0f);
    hi[j] = r.hi; lo[j] = r.lo;
  }
  size_t base = (size_t)p * TILE_STRIDE + (size_t)kt * 2 * CHUNK + slot4 * 8 + e0;
  *(half4*)&wt[base] = hi;
  *(half4*)&wt[base + CHUNK] = lo;
}

// ---------------- generic gate-weight split (Msrc x Ksrc -> MPAD x Kpad) ----------------
__global__ void k_gwsplit(const float* __restrict__ src, _Float16* __restrict__ hi,
                          _Float16* __restrict__ lo, int Msrc, int Ksrc, int Kpad,
                          int tot4) {
  int idx = blockIdx.x * blockDim.x + threadIdx.x;
  if (idx >= tot4) return;
  size_t i4 = (size_t)idx * 4;
  int m = (int)(i4 / Kpad), k = (int)(i4 % Kpad);
  half4 h, l;
#pragma unroll
  for (int j = 0; j < 4; ++j) {
    float x = (m < Msrc && k + j < Ksrc) ? src[(size_t)m * Ksrc + k + j] : 0.0f;
    hl16 r = split16(x, 64.0f);
    h[j] = r.hi; l[j] = r.lo;
  }
  *(half4*)&hi[i4] = h;
  *(half4*)&lo[i4] = l;
}

// ---------------- MFMA gates: 64j x 64b blocks, 4 waves (32x32), merged acc ----
__global__ __launch_bounds__(256, 4)
void k_gates2(const _Float16* __restrict__ wih_hi, const _Float16* __restrict__ wih_lo,
              const _Float16* __restrict__ whh_hi, const _Float16* __restrict__ whh_lo,
              const _Float16* __restrict__ x_hi, const _Float16* __restrict__ x_lo,
              const _Float16* __restrict__ h_hi, const _Float16* __restrict__ h_lo,
              float* __restrict__ gi, float* __restrict__ gh) {
  const int zz = blockIdx.z;
  const _Float16* __restrict__ Whi = zz ? whh_hi : wih_hi;
  const _Float16* __restrict__ Wlo = zz ? whh_lo : wih_lo;
  const _Float16* __restrict__ Xhi = zz ? h_hi : x_hi;
  const _Float16* __restrict__ Xlo = zz ? h_lo : x_lo;
  const int Kz = zz ? KP : KIH;
  float* __restrict__ out = zz ? gh : gi;

  const int jbase = blockIdx.x * 64;
  const int bbase = blockIdx.y * 64;
  __shared__ float4 lds[2][4][256];   // [buf][whi,wlo,xhi,xlo][kc*64+row]
  const int tid = threadIdx.x, lane = tid & 63, wid = tid >> 6;
  const int wj = wid >> 1, wb2 = wid & 1;
  const size_t wrow = (size_t)(jbase + lane) * Kz;   // stage: kc=wid, row=lane
  const size_t xrow = (size_t)(bbase + lane) * Kz;

  f32x4 acc[2][2];
#pragma unroll
  for (int i = 0; i < 2; ++i)
#pragma unroll
    for (int j = 0; j < 2; ++j) acc[i][j] = (f32x4)0.0f;

#define GSTAGE(bf, k0)                                                   \
  {                                                                      \
    gload_lds16(Whi + wrow + (k0) + wid * 8, &lds[bf][0][wid * 64]);     \
    gload_lds16(Wlo + wrow + (k0) + wid * 8, &lds[bf][1][wid * 64]);     \
    gload_lds16(Xhi + xrow + (k0) + wid * 8, &lds[bf][2][wid * 64]);     \
    gload_lds16(Xlo + xrow + (k0) + wid * 8, &lds[bf][3][wid * 64]);     \
  }

  const int nt = Kz / 32;
  GSTAGE(0, 0)
  for (int kt = 0; kt < nt; ++kt) {
    const int cur = kt & 1;
    __syncthreads();                       // drains staged loads for buf[cur]
    if (kt + 1 < nt) GSTAGE(cur ^ 1, (kt + 1) * 32)
    const int kcf = (lane >> 4) * 64 + (lane & 15);
    half8 a_hi[2], a_lo[2];
#pragma unroll
    for (int fv = 0; fv < 2; ++fv) {
      int s = kcf + wj * 32 + fv * 16;
      a_hi[fv] = *(const half8*)&lds[cur][0][s];
      a_lo[fv] = *(const half8*)&lds[cur][1][s];
    }
#pragma unroll
    for (int fb = 0; fb < 2; ++fb) {
      int s = kcf + wb2 * 32 + fb * 16;
      half8 b_hi = *(const half8*)&lds[cur][2][s];
      half8 b_lo = *(const half8*)&lds[cur][3][s];
#pragma unroll
      for (int fv = 0; fv < 2; ++fv) {
        acc[fv][fb] = __builtin_amdgcn_mfma_f32_16x16x32_f16(a_hi[fv], b_hi,
                                                             acc[fv][fb], 0, 0, 0);
        acc[fv][fb] = __builtin_amdgcn_mfma_f32_16x16x32_f16(a_hi[fv], b_lo,
                                                             acc[fv][fb], 0, 0, 0);
        acc[fv][fb] = __builtin_amdgcn_mfma_f32_16x16x32_f16(a_lo[fv], b_hi,
                                                             acc[fv][fb], 0, 0, 0);
      }
    }
  }
#undef GSTAGE

  const float c2 = 1.0f / 512.0f;
#pragma unroll
  for (int fb = 0; fb < 2; ++fb) {
    const int b = bbase + wb2 * 32 + fb * 16 + (lane & 15);
#pragma unroll
    for (int fv = 0; fv < 2; ++fv) {
#pragma unroll
      for (int r = 0; r < 4; ++r) {
        int j = jbase + wj * 32 + fv * 16 + (lane >> 4) * 4 + r;
        if (j < G3) out[b * G3 + j] = acc[fv][fb][r] * c2;
      }
    }
  }
}

// ---------------- fp32 gates fallback ----------------
__global__ void k_gates(const float* __restrict__ W_ih, const float* __restrict__ W_hh,
                        const float* __restrict__ emb_w, const float* __restrict__ hprev,
                        const int* __restrict__ tok,
                        float* __restrict__ gi, float* __restrict__ gh) {
  const int zz = blockIdx.z;
  const float* __restrict__ W = zz ? W_hh : W_ih;
  const int K = zz ? HID : EMB;
  float* __restrict__ out = zz ? gh : gi;
  __shared__ float w_lds[20][36];
  __shared__ float xh_lds[20][36];
  const int jbase = blockIdx.x * 32;
  const int bbase = blockIdx.y * 32;
  const int tid = threadIdx.x;
  const int tj = tid % 16, tb = tid / 16;
  float a00 = 0.f, a01 = 0.f, a10 = 0.f, a11 = 0.f;
  for (int k0 = 0; k0 < K; k0 += 20) {
    for (int idx = tid; idx < 640; idx += 256) {
      int col = idx / 20, kk = idx % 20;
      int j = jbase + col;
      w_lds[kk][col] = (j < G3) ? W[j * K + k0 + kk] : 0.0f;
      int b = bbase + col;
      float xv;
      if (zz) xv = hprev[b * HID + k0 + kk];
      else    xv = emb_w[tok[b] * EMB + k0 + kk];
      xh_lds[kk][col] = xv;
    }
    __syncthreads();
#pragma unroll
    for (int kk = 0; kk < 20; ++kk) {
      float w0 = w_lds[kk][tj * 2], w1 = w_lds[kk][tj * 2 + 1];
      float h0 = xh_lds[kk][tb * 2], h1 = xh_lds[kk][tb * 2 + 1];
      a00 += w0 * h0; a01 += w0 * h1;
      a10 += w1 * h0; a11 += w1 * h1;
    }
    __syncthreads();
  }
  int j0 = jbase + tj * 2, b0 = bbase + tb * 2;
  if (j0 < G3)     { out[b0 * G3 + j0] = a00;     out[(b0 + 1) * G3 + j0] = a01; }
  if (j0 + 1 < G3) { out[b0 * G3 + j0 + 1] = a10; out[(b0 + 1) * G3 + j0 + 1] = a11; }
}

// ---------------- pointwise GRU update + h fp16-split (linear for gates, tiled for logits)
__global__ void k_hnew(const float* __restrict__ gi, const float* __restrict__ gh,
                       const float* __restrict__ b_ih, const float* __restrict__ b_hh,
                       const float* __restrict__ hprev, float* __restrict__ hnext,
                       float* __restrict__ hy, _Float16* __restrict__ h_hi,
                       _Float16* __restrict__ h_lo, _Float16* __restrict__ ht, int t) {
  int idx = blockIdx.x * blockDim.x + threadIdx.x;
  if (idx >= B * HID) return;
  int b = idx / HID, i = idx % HID;
  float ir = gi[b * G3 + i]            + b_ih[i];
  float iz = gi[b * G3 + HID + i]      + b_ih[HID + i];
  float in_ = gi[b * G3 + 2 * HID + i] + b_ih[2 * HID + i];
  float hr = gh[b * G3 + i]            + b_hh[i];
  float hz = gh[b * G3 + HID + i]      + b_hh[HID + i];
  float hn = gh[b * G3 + 2 * HID + i]  + b_hh[2 * HID + i];
  float r  = 1.0f / (1.0f + expf(-(ir + hr)));
  float zg = 1.0f / (1.0f + expf(-(iz + hz)));
  float n  = tanhf(in_ + r * hn);
  float h  = (1.0f - zg) * n + zg * hprev[idx];
  hnext[idx] = h;
  hy[(size_t)b * SEQ * HID + (size_t)t * HID + i] = h;
  hl16 rr = split16(h, 8.0f);
  h_hi[b * KP + i] = rr.hi;
  h_lo[b * KP + i] = rr.lo;
  // tiled image for k_logits5: c=b>>7 (128-row halves), row=b&127,
  // kt=i>>5, kc=(i>>3)&3, e=i&7
  int c = b >> 7, row = b & 127;
  size_t tb = (size_t)c * TILE_STRIDE + (size_t)(i >> 5) * 2 * CHUNK
            + ((((i >> 3) & 3) * 128 + row) * 8) + (i & 7);
  ht[tb] = rr.hi;
  ht[tb + CHUNK] = rr.lo;
}

// ---------------- MFMA logits v6: 32x64 wave tiles, merged acc, 4 waves/SIMD ----
// Item = (panel p, v-half vh, b-half c): block covers 64v x 128b with 4 waves
// (wv in {0,1} x wb in {0,1}), each 32v x 64b -> acc only 8 f32x4. b-coverage
// 128 keeps w duplication at 2 (the r8 lesson). h LDS-staged (32KB dbuf,
// shared by all 4 waves); w direct-to-reg, double-buffered, issued before the
// MFMA body so its latency hides under compute.
__global__ __launch_bounds__(256, 4)
void k_logits5(const _Float16* __restrict__ wt, const _Float16* __restrict__ ht,
               const float* __restrict__ out_b, const uint32_t* __restrict__ keys,
               unsigned long long* __restrict__ slot, int t) {
  const int item = (blockIdx.x & 7) * 197 + (blockIdx.x >> 3);  // XCD-chunked
  if (item >= NIT5) return;
  const int p = item >> 2, vh = (item >> 1) & 1, c = item & 1;

  __shared__ float4 ldsh[2][1024];   // [buf][part*512 + kc*128 + row]
  const int tid = threadIdx.x, lane = tid & 63, wid = tid >> 6;
  const int wv = wid >> 1, wb = wid & 1;
  const int lq = lane >> 4, lr = lane & 15;

  const _Float16* __restrict__ wp = wt + (size_t)p * TILE_STRIDE;
  const _Float16* __restrict__ hp = ht + (size_t)c * TILE_STRIDE;

  const int wslot = lq * 128 + vh * 64 + wv * 32 + lr;   // + fv*16
  const int hslot = lq * 128 + wb * 64 + lr;             // + fb*16 (+part*512)

  f32x4 acc[2][4];
#pragma unroll
  for (int i = 0; i < 2; ++i)
#pragma unroll
    for (int j = 0; j < 4; ++j) acc[i][j] = (f32x4)0.0f;

  half8 wA[4], wB[4];   // [fv*2 + part]

#define LOADW(W, ktv)                                                         \
  {                                                                           \
    const _Float16* bw = wp + (size_t)(ktv) * (2 * CHUNK);                    \
    _Pragma("unroll")                                                         \
    for (int fv = 0; fv < 2; ++fv) {                                          \
      W[fv * 2 + 0] = *(const half8*)(bw + (wslot + fv * 16) * 8);            \
      W[fv * 2 + 1] = *(const half8*)(bw + CHUNK + (wslot + fv * 16) * 8);    \
    }                                                                         \
  }
#define STAGEH(bf, ktv)                                                       \
  {                                                                           \
    const _Float16* bh = hp + (size_t)(ktv) * (2 * CHUNK);                    \
    _Pragma("unroll")                                                         \
    for (int j = 0; j < 4; ++j)                                               \
      gload_lds16(bh + (j * 256 + wid * 64 + lane) * 8,                       \
                  &ldsh[bf][j * 256 + wid * 64]);                             \
  }
#define COMPUTE(bf, W)                                                        \
  _Pragma("unroll")                                                           \
  for (int fb = 0; fb < 4; ++fb) {                                            \
    half8 hhi = *(const half8*)&ldsh[bf][hslot + fb * 16];                    \
    half8 hlo = *(const half8*)&ldsh[bf][512 + hslot + fb * 16];              \
    _Pragma("unroll")                                                         \
    for (int fv = 0; fv < 2; ++fv) {                                          \
      acc[fv][fb] = __builtin_amdgcn_mfma_f32_16x16x32_f16(                   \
          W[fv * 2 + 0], hhi, acc[fv][fb], 0, 0, 0);                          \
      acc[fv][fb] = __builtin_amdgcn_mfma_f32_16x16x32_f16(                   \
          W[fv * 2 + 0], hlo, acc[fv][fb], 0, 0, 0);                          \
      acc[fv][fb] = __builtin_amdgcn_mfma_f32_16x16x32_f16(                   \
          W[fv * 2 + 1], hhi, acc[fv][fb], 0, 0, 0);                          \
    }                                                                         \
  }

  LOADW(wA, 0)
  STAGEH(0, 0)
  __syncthreads();
#pragma unroll 1
  for (int kt = 0; kt < NKT; kt += 2) {
    if (kt + 1 < NKT) { STAGEH(1, kt + 1) LOADW(wB, kt + 1) }
    COMPUTE(0, wA)
    __syncthreads();    // waves done with buf0; drains stage(1)+wB
    if (kt + 2 < NKT) { STAGEH(0, kt + 2) LOADW(wA, kt + 2) }
    COMPUTE(1, wB)
    __syncthreads();    // waves done with buf1; drains stage(0)+wA
  }
#undef LOADW
#undef STAGEH
#undef COMPUTE

  const uint32_t key0 = keys[2 * t], key1 = keys[2 * t + 1];
  const float c2 = 1.0f / 512.0f;
  const int vbase0 = p * 128 + vh * 64 + wv * 32;
#pragma unroll
  for (int fb = 0; fb < 4; ++fb) {
    const int b = c * 128 + wb * 64 + fb * 16 + lr;
    unsigned long long best = 0ull;
#pragma unroll
    for (int fv = 0; fv < 2; ++fv) {
#pragma unroll
      for (int r = 0; r < 4; ++r) {
        int v = vbase0 + fv * 16 + lq * 4 + r;
        if (v < VOCAB) {
          float s = acc[fv][fb][r] * c2 + out_b[v];
          unsigned long long cand = gumbel_pack(s, key0, key1, b, v);
          if (cand > best) best = cand;
        }
      }
    }
    unsigned long long o;
    o = __shfl_xor(best, 16, 64); if (o > best) best = o;
    o = __shfl_xor(best, 32, 64); if (o > best) best = o;
    if (lq == 0) atomicMax(&slot[b], best);
  }
}

// ---------------- fp32 logits fallback ----------------
#define WPITCH 68
#define HPITCH 260
__global__ __launch_bounds__(256)
void k_logits_f32(const float* __restrict__ h, const float* __restrict__ out_w,
                  const float* __restrict__ out_b, const uint32_t* __restrict__ keys,
                  unsigned long long* __restrict__ slot, int t) {
  __shared__ float w_lds[20][WPITCH];
  __shared__ float h_lds[20][HPITCH];
  const int vbase = blockIdx.x * 64;
  const int tid = threadIdx.x;
  const int tv = tid % 8, tb = tid / 8;
  float acc[8][8];
#pragma unroll
  for (int i = 0; i < 8; ++i)
#pragma unroll
    for (int j = 0; j < 8; ++j) acc[i][j] = 0.f;

  for (int k0 = 0; k0 < HID; k0 += 20) {
    for (int idx = tid; idx < 64 * 20; idx += 256) {
      int vv = idx / 20, kk = idx % 20;
      int v = vbase + vv;
      w_lds[kk][vv] = (v < VOCAB) ? out_w[(size_t)v * HID + k0 + kk] : 0.0f;
    }
    for (int idx = tid; idx < 256 * 20; idx += 256) {
      int bb = idx / 20, kk = idx % 20;
      h_lds[kk][bb] = h[bb * HID + k0 + kk];
    }
    __syncthreads();
#pragma unroll
    for (int kk = 0; kk < 20; ++kk) {
      float wv[8], hv[8];
      *(float4*)&wv[0] = *(const float4*)&w_lds[kk][tv * 8];
      *(float4*)&wv[4] = *(const float4*)&w_lds[kk][tv * 8 + 4];
      *(float4*)&hv[0] = *(const float4*)&h_lds[kk][tb * 8];
      *(float4*)&hv[4] = *(const float4*)&h_lds[kk][tb * 8 + 4];
#pragma unroll
      for (int iv = 0; iv < 8; ++iv)
#pragma unroll
        for (int ib = 0; ib < 8; ++ib) acc[iv][ib] += wv[iv] * hv[ib];
    }
    __syncthreads();
  }

  const uint32_t key0 = keys[2 * t], key1 = keys[2 * t + 1];
#pragma unroll
  for (int ib = 0; ib < 8; ++ib) {
    const int b = tb * 8 + ib;
    unsigned long long best = 0ull;
#pragma unroll
    for (int iv = 0; iv < 8; ++iv) {
      int v = vbase + tv * 8 + iv;
      if (v >= VOCAB) continue;
      unsigned long long cand = gumbel_pack(acc[iv][ib] + out_b[v], key0, key1, b, v);
      if (cand > best) best = cand;
    }
#pragma unroll
    for (int off = 1; off < 8; off <<= 1) {
      unsigned long long other = __shfl_xor(best, off, 64);
      if (other > best) best = other;
    }
    if (tv == 0) atomicMax(&slot[b], best);
  }
}

// ---------------- token extraction + emb gather/split ----------------
__global__ void k_tok2(const unsigned long long* __restrict__ slot,
                       const float* __restrict__ emb_w,
                       int* __restrict__ tok_next, float* __restrict__ y_out,
                       _Float16* __restrict__ xc_hi, _Float16* __restrict__ xc_lo,
                       int t, int full) {
  const int b = blockIdx.x;
  const int c = threadIdx.x;   // 128 threads
  unsigned long long p = slot[b];
  uint32_t v = ~((uint32_t)(p & 0xFFFFFFFFull));
  if (c == 0) {
    tok_next[b] = (int)v;
    y_out[b * SEQ + t] = (float)v;
  }
  if (!full) return;
  if (c < 75) {
    float4 xv = *(const float4*)&emb_w[(size_t)v * EMB + c * 4];
    half4 hi, lo;
    hl16 r0 = split16(xv.x, 8.0f); hi[0] = r0.hi; lo[0] = r0.lo;
    hl16 r1 = split16(xv.y, 8.0f); hi[1] = r1.hi; lo[1] = r1.lo;
    hl16 r2 = split16(xv.z, 8.0f); hi[2] = r2.hi; lo[2] = r2.lo;
    hl16 r3 = split16(xv.w, 8.0f); hi[3] = r3.hi; lo[3] = r3.lo;
    *(half4*)&xc_hi[b * KIH + c * 4] = hi;
    *(half4*)&xc_lo[b * KIH + c * 4] = lo;
  } else if (c < 80) {
    *(half4*)&xc_hi[b * KIH + c * 4] = (half4)(_Float16)0.0f;
    *(half4*)&xc_lo[b * KIH + c * 4] = (half4)(_Float16)0.0f;
  }
}

// ---------------- host launch ----------------
extern "C" void kernel_launch(void* const* d_in, const int* in_sizes, int n_in,
                              void* d_out, int out_size, void* d_ws, size_t ws_size,
                              hipStream_t stream) {
  const float* z      = (const float*)d_in[0];
  const int*   l      = (const int*)  d_in[1];
  const float* emb_w  = (const float*)d_in[2];
  const float* attr_w = (const float*)d_in[3];
  const float* W_ih   = (const float*)d_in[4];
  const float* W_hh   = (const float*)d_in[5];
  const float* b_ih   = (const float*)d_in[6];
  const float* b_hh   = (const float*)d_in[7];
  const float* out_w  = (const float*)d_in[8];
  const float* out_b  = (const float*)d_in[9];

  float* hy    = (float*)d_out;
  float* y_out = (float*)d_out + HY_ELEMS;

  char* ws = (char*)d_ws;
  size_t off = 0;
  uint32_t* keys            = (uint32_t*)(ws + off);           off += 256;
  unsigned long long* slots = (unsigned long long*)(ws + off); off += (size_t)MAXLEN * B * 8;
  int* tokbuf               = (int*)(ws + off);                off += (size_t)32 * B * 4;
  float* hbuf               = (float*)(ws + off);              off += (size_t)2 * B * HID * 4;
  float* gi                 = (float*)(ws + off);              off += (size_t)B * G3 * 4;
  float* gh                 = (float*)(ws + off);              off += (size_t)B * G3 * 4;
  _Float16* h_hi            = (_Float16*)(ws + off);           off += (size_t)B * KP * 2;
  _Float16* h_lo            = (_Float16*)(ws + off);           off += (size_t)B * KP * 2;
  _Float16* ht              = (_Float16*)(ws + off);           off += (size_t)2 * TILE_STRIDE * 2;
  _Float16* wt              = (_Float16*)(ws + off);           off += (size_t)NVT * TILE_STRIDE * 2;
  const size_t tier1_end = off;
  _Float16* wih_hi          = (_Float16*)(ws + off);           off += (size_t)MPAD * KIH * 2;
  _Float16* wih_lo          = (_Float16*)(ws + off);           off += (size_t)MPAD * KIH * 2;
  _Float16* whh_hi          = (_Float16*)(ws + off);           off += (size_t)MPAD * KP * 2;
  _Float16* whh_lo          = (_Float16*)(ws + off);           off += (size_t)MPAD * KP * 2;
  _Float16* x0_hi           = (_Float16*)(ws + off);           off += (size_t)B * KIH * 2;
  _Float16* x0_lo           = (_Float16*)(ws + off);           off += (size_t)B * KIH * 2;
  _Float16* xe_hi           = (_Float16*)(ws + off);           off += (size_t)B * KIH * 2;
  _Float16* xe_lo           = (_Float16*)(ws + off);           off += (size_t)B * KIH * 2;
  _Float16* xc_hi           = (_Float16*)(ws + off);           off += (size_t)B * KIH * 2;
  _Float16* xc_lo           = (_Float16*)(ws + off);           off += (size_t)B * KIH * 2;
  const size_t tier2_end = off;
  const int tier = (ws_size >= tier2_end) ? 2 : ((ws_size >= tier1_end) ? 1 : 0);

  k_init<<<(B * HID + 255) / 256, 256, 0, stream>>>(
      z, l, attr_w, emb_w, hbuf, keys, slots, tokbuf, y_out, h_hi, h_lo, ht,
      x0_hi, x0_lo, xe_hi, xe_lo, (tier == 2) ? 1 : 0);

  if (tier >= 1) {
    size_t tot = (size_t)NVT * NKT * 1024;
    k_wsplit<<<(int)((tot + 255) / 256), 256, 0, stream>>>(out_w, wt);
  }
  if (tier == 2) {
    int tih = MPAD * KIH / 4, thh = MPAD * KP / 4;
    k_gwsplit<<<(tih + 255) / 256, 256, 0, stream>>>(W_ih, wih_hi, wih_lo, G3, EMB, KIH, tih);
    k_gwsplit<<<(thh + 255) / 256, 256, 0, stream>>>(W_hh, whh_hi, whh_lo, G3, HID, KP, thh);
  }

  for (int t = 0; t <= MAXLEN; ++t) {
    float* hprev = hbuf + (t % 2) * B * HID;
    float* hnext = hbuf + ((t + 1) % 2) * B * HID;

    if (tier == 2) {
      const _Float16* xh = (t == 0) ? x0_hi : ((t == MAXLEN) ? xe_hi : xc_hi);
      const _Float16* xl = (t == 0) ? x0_lo : ((t == MAXLEN) ? xe_lo : xc_lo);
      dim3 g2(33, 4, 2);
      k_gates2<<<g2, 256, 0, stream>>>(wih_hi, wih_lo, whh_hi, whh_lo,
                                       xh, xl, h_hi, h_lo, gi, gh);
    } else {
      const int* tok_t = tokbuf + ((t == MAXLEN) ? 31 : t) * B;
      dim3 ggrid(66, 8, 2);
      k_gates<<<ggrid, 256, 0, stream>>>(W_ih, W_hh, emb_w, hprev, tok_t, gi, gh);
    }
    k_hnew<<<(B * HID + 255) / 256, 256, 0, stream>>>(gi, gh, b_ih, b_hh, hprev,
                                                      hnext, hy, h_hi, h_lo, ht, t);
    if (t < MAXLEN) {
      if (tier >= 1) {
        k_logits5<<<NBLK5, 256, 0, stream>>>(wt, ht, out_b, keys,
                                             slots + (size_t)t * B, t);
      } else {
        k_logits_f32<<<(VOCAB + 63) / 64, 256, 0, stream>>>(hnext, out_w, out_b, keys,
                                                            slots + (size_t)t * B, t);
      }
      k_tok2<<<B, 128, 0, stream>>>(slots + (size_t)t * B, emb_w,
                                    tokbuf + (t + 1) * B, y_out, xc_hi, xc_lo,
                                    t, (tier == 2) ? 1 : 0);
    }
  }
}